// Round 6
// baseline (352.104 us; speedup 1.0000x reference)
//
#include <hip/hip_runtime.h>

// pred, target: [32,1,1024,1024] f32 -> scalar f32 = mean((softplus(p)-p*t)*w),
// w = 0.1 on 5x5 morphological gradient of binarized target, gated on
// cond = (t.max()==1 && t.min()==0).
//
// R6: 3-kernel decoupled streaming (R3/R5 post-mortem: cross-lane dependency
// chains serialize waves; neither VALU nor HBM above 31%).
//  k_mask: target -> interleaved ballot bitmask Bm (4 MB ws) + exact min/max.
//  k_edge: 5x5 morph gradient on Bm (bit logic, L1-hot) -> Em (4 MB ws).
//  k_loss: pred stream + per-thread bit extraction -> two double sums.
// Interleaved bit convention (verified R2/R5): word W=4*it+m, bit l
// <-> col 256*it + 4*l + m within a row.
// Fallback to R5-verified fused kernel if ws_size too small.

#define IMG   1024
#define NTOT  33554432.0
#define NF4   8388608LL            // total float4s = 32*1024*256
#define GRID  2048

typedef unsigned long long u64;

__device__ __forceinline__ unsigned encf(float f) {
    unsigned u = __float_as_uint(f);
    return (u & 0x80000000u) ? ~u : (u | 0x80000000u);
}
__device__ __forceinline__ float decf(unsigned e) {
    unsigned u = (e & 0x80000000u) ? (e & 0x7fffffffu) : ~e;
    return __uint_as_float(u);
}

__global__ void bbl_init(double* dws, unsigned* uws) {
    if (threadIdx.x == 0) {
        dws[0] = 0.0; dws[1] = 0.0;
        uws[0] = 0xFFFFFFFFu;   // running min (encoded)
        uws[1] = 0u;            // running max (encoded)
    }
}

// ---- k1: bitmask build + exact min/max ------------------------------------
__global__ __launch_bounds__(256) void bbl_mask(
        const float* __restrict__ target, u64* __restrict__ Bm,
        unsigned* __restrict__ uws) {
    __shared__ unsigned rmn[4], rmx[4];
    const int tid = threadIdx.x, lane = tid & 63, wid = tid >> 6;
    const long long stride = (long long)GRID * 256;
    float vmin = 3.4e38f, vmax = -3.4e38f;

    for (long long q = (long long)blockIdx.x * 256 + tid; q < NF4; q += stride) {
        float4 v = ((const float4*)target)[q];
        vmin = fminf(vmin, fminf(fminf(v.x, v.y), fminf(v.z, v.w)));
        vmax = fmaxf(vmax, fmaxf(fmaxf(v.x, v.y), fmaxf(v.z, v.w)));
        u64 b0 = __ballot(v.x > 0.5f);
        u64 b1 = __ballot(v.y > 0.5f);
        u64 b2 = __ballot(v.z > 0.5f);
        u64 b3 = __ballot(v.w > 0.5f);
        if (lane < 4) {
            u64 val = (lane == 0) ? b0 : (lane == 1) ? b1 : (lane == 2) ? b2 : b3;
            long long q0 = q - lane;          // lane-0's q (q contiguous in wave)
            Bm[(q0 >> 4) + lane] = val;       // word base 4*(q0>>6), +lane
        }
    }
    // exact min/max reduce: wave shuffle -> LDS -> 2 atomics/block
    for (int off = 32; off > 0; off >>= 1) {
        vmin = fminf(vmin, __shfl_down(vmin, off));
        vmax = fmaxf(vmax, __shfl_down(vmax, off));
    }
    if (lane == 0) { rmn[wid] = encf(vmin); rmx[wid] = encf(vmax); }
    __syncthreads();
    if (tid == 0) {
        unsigned mn = rmn[0], mx = rmx[0];
        #pragma unroll
        for (int i = 1; i < 4; ++i) { mn = min(mn, rmn[i]); mx = max(mx, rmx[i]); }
        atomicMin(&uws[0], mn);
        atomicMax(&uws[1], mx);
    }
}

// ---- k2: 5x5 morphological gradient on the bitmask ------------------------
__global__ __launch_bounds__(256) void bbl_edge(
        const u64* __restrict__ Bm, u64* __restrict__ Em) {
    const int t  = blockIdx.x * 256 + threadIdx.x;   // 0..524287 word id
    const int w  = t & 15;                           // word in row
    const int rw = t >> 4;                           // global row id
    const int r  = rw & 1023;
    const u64* B = Bm + (((long long)(rw >> 10)) << 14);  // image base
    const int lo = max(r - 2, 0), hi = min(r + 2, IMG - 1);

    // vertical OR/AND for words w-3..w+3 (OOB word -> reduce identity)
    u64 vd[7], ve[7];
    #pragma unroll
    for (int j = 0; j < 7; ++j) {
        const int wj = w - 3 + j;
        if (wj < 0 || wj > 15) { vd[j] = 0ULL; ve[j] = ~0ULL; }
        else {
            u64 o = 0ULL, a = ~0ULL;
            for (int g = lo; g <= hi; ++g) { u64 b = B[g * 16 + wj]; o |= b; a &= b; }
            vd[j] = o; ve[j] = a;
        }
    }
    // horizontal +-2 in interleaved domain (derivation matches R2-verified 1c):
    // out word W=4it+k bit l <- col +delta: kp=k+delta in [0,3] -> aligned word
    // W+delta; kp>3 -> (W+delta-4)>>1 | (W+delta)<<63; kp<0 -> mirror.
    const int k = w & 3;
    u64 hd = vd[3], he = ve[3];
    #pragma unroll
    for (int di = 0; di < 4; ++di) {
        const int d = (di < 2) ? di - 2 : di - 1;    // -2,-1,1,2
        const int kp = k + d;
        u64 td, te;
        if (kp >= 0 && kp <= 3) { td = vd[3 + d];                     te = ve[3 + d]; }
        else if (kp > 3)        { td = (vd[3 + d - 4] >> 1) | (vd[3 + d] << 63);
                                  te = (ve[3 + d - 4] >> 1) | (ve[3 + d] << 63); }
        else                    { td = (vd[3 + d + 4] << 1) | (vd[3 + d] >> 63);
                                  te = (ve[3 + d + 4] << 1) | (ve[3 + d] >> 63); }
        hd |= td; he &= te;
    }
    Em[t] = hd & ~he;   // dilated==1 && eroded==0  <=> gradient>0
}

// ---- k3: loss stream ------------------------------------------------------
__global__ __launch_bounds__(256) void bbl_loss(
        const float* __restrict__ pred, const u64* __restrict__ Bm,
        const u64* __restrict__ Em, double* __restrict__ dws) {
    __shared__ float rs1[4], rse[4];
    const int tid = threadIdx.x, lane = tid & 63, wid = tid >> 6;
    const long long stride = (long long)GRID * 256;
    float s1 = 0.f, se = 0.f;

    for (long long q = (long long)blockIdx.x * 256 + tid; q < NF4; q += stride) {
        float4 p = ((const float4*)pred)[q];
        const long long wb = (q >> 6) << 2;          // word base for this 256-col group
        const int l = (int)(q & 63);                 // my bit position
        u64 t0 = Bm[wb + 0], t1 = Bm[wb + 1], t2 = Bm[wb + 2], t3 = Bm[wb + 3];
        u64 e0 = Em[wb + 0], e1 = Em[wb + 1], e2 = Em[wb + 2], e3 = Em[wb + 3];
        float x, loss;
        x = p.x;
        loss = fmaxf(x, 0.f) + __logf(1.f + __expf(-fabsf(x)))
             - (((t0 >> l) & 1ULL) ? x : 0.f);
        s1 += loss; se += ((e0 >> l) & 1ULL) ? loss : 0.f;
        x = p.y;
        loss = fmaxf(x, 0.f) + __logf(1.f + __expf(-fabsf(x)))
             - (((t1 >> l) & 1ULL) ? x : 0.f);
        s1 += loss; se += ((e1 >> l) & 1ULL) ? loss : 0.f;
        x = p.z;
        loss = fmaxf(x, 0.f) + __logf(1.f + __expf(-fabsf(x)))
             - (((t2 >> l) & 1ULL) ? x : 0.f);
        s1 += loss; se += ((e2 >> l) & 1ULL) ? loss : 0.f;
        x = p.w;
        loss = fmaxf(x, 0.f) + __logf(1.f + __expf(-fabsf(x)))
             - (((t3 >> l) & 1ULL) ? x : 0.f);
        s1 += loss; se += ((e3 >> l) & 1ULL) ? loss : 0.f;
    }

    for (int off = 32; off > 0; off >>= 1) {
        s1 += __shfl_down(s1, off);
        se += __shfl_down(se, off);
    }
    if (lane == 0) { rs1[wid] = s1; rse[wid] = se; }
    __syncthreads();
    if (tid == 0) {
        float S1 = rs1[0] + rs1[1] + rs1[2] + rs1[3];
        float Se = rse[0] + rse[1] + rse[2] + rse[3];
        atomicAdd(&dws[0], (double)S1);
        atomicAdd(&dws[1], (double)Se);
    }
}

__global__ void bbl_fin(const double* __restrict__ dws,
                        const unsigned* __restrict__ uws,
                        float* __restrict__ out) {
    if (threadIdx.x == 0) {
        float fmin = decf(uws[0]);
        float fmax = decf(uws[1]);
        bool cond = (fmax == 1.0f) && (fmin == 0.0f);
        double s = cond ? (dws[0] - 0.9 * dws[1]) : dws[0];
        out[0] = (float)(s / NTOT);
    }
}

// ---- fallback (R5-verified fused kernel) if ws too small ------------------
__device__ __forceinline__ u64 shfl64(u64 v, int src) {
    unsigned lo = (unsigned)__shfl((int)(unsigned)(v & 0xffffffffULL), src, 64);
    unsigned hi = (unsigned)__shfl((int)(unsigned)(v >> 32), src, 64);
    return ((u64)hi << 32) | lo;
}
__device__ __forceinline__ u64 bcast64(u64 v, int srcImm) {
    unsigned lo = (unsigned)__builtin_amdgcn_readlane((int)(unsigned)(v & 0xffffffffULL), srcImm);
    unsigned hi = (unsigned)__builtin_amdgcn_readlane((int)(unsigned)(v >> 32), srcImm);
    return ((u64)hi << 32) | lo;
}

__global__ __launch_bounds__(256) void bbl_fallback(
        const float* __restrict__ pred,
        const float* __restrict__ target,
        double* __restrict__ dws, unsigned* __restrict__ uws) {
    __shared__ float    redS1[4], redSe[4];
    __shared__ unsigned redMn[4], redMx[4];
    const int tid = threadIdx.x, lane = tid & 63, wid = tid >> 6;
    const int gw = blockIdx.x * 4 + wid;
    const int img = gw >> 7;
    const int r0 = (gw & 127) * 8;
    const size_t base = (size_t)img * IMG * IMG;
    const float* tbase = target + base;
    const float* pbase = pred + base;
    const int w = lane & 15, k = w & 3;
    float vmin = 3.4e38f, vmax = -3.4e38f, s1 = 0.f, se = 0.f;

    auto loadrow = [&](int gr, bool mm) -> u64 {
        const float4* rp = (const float4*)(tbase + (size_t)gr * IMG);
        u64 myw = 0ULL;
        #pragma unroll
        for (int it = 0; it < 4; ++it) {
            float4 v = rp[it * 64 + lane];
            if (mm) {
                vmin = fminf(vmin, fminf(fminf(v.x, v.y), fminf(v.z, v.w)));
                vmax = fmaxf(vmax, fmaxf(fmaxf(v.x, v.y), fmaxf(v.z, v.w)));
            }
            u64 b0 = __ballot(v.x > 0.5f), b1 = __ballot(v.y > 0.5f);
            u64 b2 = __ballot(v.z > 0.5f), b3 = __ballot(v.w > 0.5f);
            u64 bw = (k == 0) ? b0 : (k == 1) ? b1 : (k == 2) ? b2 : b3;
            if ((w >> 2) == it) myw = bw;
        }
        return myw;
    };

    u64 q0 = loadrow(max(r0 - 2, 0), false);
    u64 q1 = loadrow(max(r0 - 1, 0), false);
    u64 q2 = loadrow(r0, true);
    u64 q3 = loadrow(r0 + 1, true);

    for (int r = r0; r < r0 + 8; ++r) {
        const int nr = min(r + 2, IMG - 1);
        u64 q4 = loadrow(nr, r + 2 <= r0 + 7);
        const float4* pp = (const float4*)(pbase + (size_t)r * IMG);
        float4 p0 = pp[0 * 64 + lane], p1 = pp[1 * 64 + lane];
        float4 p2 = pp[2 * 64 + lane], p3 = pp[3 * 64 + lane];
        u64 vd = q0 | q1 | q2 | q3 | q4;
        u64 ve = q0 & q1 & q2 & q3 & q4;
        u64 ct = q2, hd = vd, he = ve;
        #pragma unroll
        for (int di = 0; di < 4; ++di) {
            const int d = (di < 2) ? di - 2 : di - 1;
            int wp = w + d;
            bool inp = (wp >= 0) && (wp < 16);
            u64 ad = shfl64(vd, wp & 15), ae = shfl64(ve, wp & 15);
            ad = inp ? ad : 0ULL; ae = inp ? ae : ~0ULL;
            int ws2 = wp + ((d > 0) ? -4 : 4);
            u64 bd = shfl64(vd, ws2 & 15), be = shfl64(ve, ws2 & 15);
            int kp = k + d;
            u64 rd, re;
            if (d > 0) {
                rd = (kp <= 3) ? ad : ((bd >> 1) | (ad << 63));
                re = (kp <= 3) ? ae : ((be >> 1) | (ae << 63));
            } else {
                rd = (kp >= 0) ? ad : ((bd << 1) | (ad >> 63));
                re = (kp >= 0) ? ae : ((be << 1) | (ae >> 63));
            }
            hd |= rd; he &= re;
        }
        u64 em = hd & ~he;
        #pragma unroll
        for (int it = 0; it < 4; ++it) {
            float4 p = (it == 0) ? p0 : (it == 1) ? p1 : (it == 2) ? p2 : p3;
            #pragma unroll
            for (int m = 0; m < 4; ++m) {
                u64 ew = bcast64(em, it * 4 + m);
                u64 tw = bcast64(ct, it * 4 + m);
                float x = (m == 0) ? p.x : (m == 1) ? p.y : (m == 2) ? p.z : p.w;
                float xt = ((tw >> lane) & 1ULL) ? x : 0.f;
                float loss = fmaxf(x, 0.f) + __logf(1.f + __expf(-fabsf(x))) - xt;
                s1 += loss; se += ((ew >> lane) & 1ULL) ? loss : 0.f;
            }
        }
        q0 = q1; q1 = q2; q2 = q3; q3 = q4;
    }
    for (int off = 32; off > 0; off >>= 1) {
        s1 += __shfl_down(s1, off); se += __shfl_down(se, off);
        vmin = fminf(vmin, __shfl_down(vmin, off));
        vmax = fmaxf(vmax, __shfl_down(vmax, off));
    }
    if (lane == 0) {
        redS1[wid] = s1; redSe[wid] = se;
        redMn[wid] = encf(vmin); redMx[wid] = encf(vmax);
    }
    __syncthreads();
    if (tid == 0) {
        float S1 = 0.f, Se = 0.f; unsigned mn = 0xFFFFFFFFu, mx = 0u;
        #pragma unroll
        for (int i = 0; i < 4; ++i) {
            S1 += redS1[i]; Se += redSe[i];
            mn = min(mn, redMn[i]); mx = max(mx, redMx[i]);
        }
        atomicAdd(&dws[0], (double)S1); atomicAdd(&dws[1], (double)Se);
        atomicMin(&uws[0], mn); atomicMax(&uws[1], mx);
    }
}

extern "C" void kernel_launch(void* const* d_in, const int* in_sizes, int n_in,
                              void* d_out, int out_size, void* d_ws, size_t ws_size,
                              hipStream_t stream) {
    const float* pred   = (const float*)d_in[0];
    const float* target = (const float*)d_in[1];
    double*   dws = (double*)d_ws;
    unsigned* uws = (unsigned*)((char*)d_ws + 16);
    float*    out = (float*)d_out;

    // workspace: [0,16) dws, [16,24) uws, [4096, 4096+4MB) Bm, then Em
    const size_t MASKB = 4194304;                 // 512K u64 words
    const size_t need  = 4096 + 2 * MASKB;
    u64* Bm = (u64*)((char*)d_ws + 4096);
    u64* Em = (u64*)((char*)d_ws + 4096 + MASKB);

    hipLaunchKernelGGL(bbl_init, dim3(1), dim3(64), 0, stream, dws, uws);
    if (ws_size >= need) {
        hipLaunchKernelGGL(bbl_mask, dim3(GRID), dim3(256), 0, stream, target, Bm, uws);
        hipLaunchKernelGGL(bbl_edge, dim3(GRID), dim3(256), 0, stream, Bm, Em);
        hipLaunchKernelGGL(bbl_loss, dim3(GRID), dim3(256), 0, stream, pred, Bm, Em, dws);
    } else {
        hipLaunchKernelGGL(bbl_fallback, dim3(1024), dim3(256), 0, stream,
                           pred, target, dws, uws);
    }
    hipLaunchKernelGGL(bbl_fin, dim3(1), dim3(64), 0, stream, dws, uws, out);
}

// Round 7
// 340.265 us; speedup vs baseline: 1.0348x; 1.0348x over previous
//
#include <hip/hip_runtime.h>

// pred, target: [32,1,1024,1024] f32 -> scalar f32 = mean((softplus(p)-p*t)*w),
// w = 0.1 on 5x5 morphological gradient of binarized target, gated on
// cond = (t.max()==1 && t.min()==0).
//
// R7: R6 3-kernel split + MLP fix. R6's VGPR_Count=12 proved the compiler kept
// ONE load in flight (grid-stride, runtime trip count). Now: compile-time
// 16 float4/thread, explicit 8-deep load staging -> 8 outstanding dwordx4/wave.
// k_edge also bit-transposes interleaved ballot words into a linear-layout
// (t,e) ulonglong2 per 64-col group, so k_loss needs only 2 loads/iteration.
//  Bm word 4it+m bit l <-> col 256it+4l+m (ballot-interleaved, R2/R6-verified)
//  TE[g] = {t-word, e-word}, bit b of group g <-> col 64g+b (linear)

#define IMG   1024
#define NTOT  33554432.0
#define NF4   8388608              // total float4s
#define GRID  2048                 // 2048*256 threads * 16 f4 = NF4

typedef unsigned long long u64;

__device__ __forceinline__ unsigned encf(float f) {
    unsigned u = __float_as_uint(f);
    return (u & 0x80000000u) ? ~u : (u | 0x80000000u);
}
__device__ __forceinline__ float decf(unsigned e) {
    unsigned u = (e & 0x80000000u) ? (e & 0x7fffffffu) : ~e;
    return __uint_as_float(u);
}
// spread 16 low bits so bit i -> bit 4i
__device__ __forceinline__ u64 spread4(u64 x) {
    x &= 0xFFFFULL;
    x = (x | (x << 24)) & 0x000000FF000000FFULL;
    x = (x | (x << 12)) & 0x000F000F000F000FULL;
    x = (x | (x <<  6)) & 0x0303030303030303ULL;
    x = (x | (x <<  3)) & 0x1111111111111111ULL;
    return x;
}

__global__ void bbl_init(double* dws, unsigned* uws) {
    if (threadIdx.x == 0) {
        dws[0] = 0.0; dws[1] = 0.0;
        uws[0] = 0xFFFFFFFFu;   // running min (encoded)
        uws[1] = 0u;            // running max (encoded)
    }
}

// ---- k1: target -> interleaved bitmask + exact min/max --------------------
__global__ __launch_bounds__(256) void bbl_mask(
        const float* __restrict__ target, u64* __restrict__ Bm,
        unsigned* __restrict__ uws) {
    __shared__ unsigned rmn[4], rmx[4];
    const int tid = threadIdx.x, lane = tid & 63, wid = tid >> 6;
    const int qb = blockIdx.x * 4096 + tid;      // float4 index, i=0
    const float4* T = (const float4*)target;
    float vmin = 3.4e38f, vmax = -3.4e38f;

    #pragma unroll
    for (int half = 0; half < 2; ++half) {
        float4 v[8];
        #pragma unroll
        for (int j = 0; j < 8; ++j) v[j] = T[qb + (half * 8 + j) * 256];
        #pragma unroll
        for (int j = 0; j < 8; ++j) {
            float4 t = v[j];
            vmin = fminf(vmin, fminf(fminf(t.x, t.y), fminf(t.z, t.w)));
            vmax = fmaxf(vmax, fmaxf(fmaxf(t.x, t.y), fmaxf(t.z, t.w)));
            u64 b0 = __ballot(t.x > 0.5f);
            u64 b1 = __ballot(t.y > 0.5f);
            u64 b2 = __ballot(t.z > 0.5f);
            u64 b3 = __ballot(t.w > 0.5f);
            if (lane < 4) {
                const int q0 = qb - lane + (half * 8 + j) * 256;  // wave-uniform
                u64 val = (lane == 0) ? b0 : (lane == 1) ? b1 : (lane == 2) ? b2 : b3;
                Bm[(q0 >> 4) + lane] = val;
            }
        }
    }
    for (int off = 32; off > 0; off >>= 1) {
        vmin = fminf(vmin, __shfl_down(vmin, off));
        vmax = fmaxf(vmax, __shfl_down(vmax, off));
    }
    if (lane == 0) { rmn[wid] = encf(vmin); rmx[wid] = encf(vmax); }
    __syncthreads();
    if (tid == 0) {
        unsigned mn = rmn[0], mx = rmx[0];
        #pragma unroll
        for (int i = 1; i < 4; ++i) { mn = min(mn, rmn[i]); mx = max(mx, rmx[i]); }
        atomicMin(&uws[0], mn);
        atomicMax(&uws[1], mx);
    }
}

// ---- k2: morph gradient on bitmask; emit linear (t,e) pairs ---------------
// thread owns one it-group (4 interleaved words = 256 cols) of one row.
__global__ __launch_bounds__(256) void bbl_edge(
        const u64* __restrict__ Bm, ulonglong2* __restrict__ TE) {
    const int t   = blockIdx.x * 256 + threadIdx.x;  // 0..131071
    const int itg = t & 3;
    const int r   = (t >> 2) & 1023;
    const int img = t >> 12;
    const u64* B  = Bm + img * 16384;
    const int lo = max(r - 2, 0), hi = min(r + 2, IMG - 1);
    const int w0 = 4 * itg - 4;

    // vertical OR/AND over 5 rows for words w0..w0+11 (OOB word -> identity)
    u64 vd[12], ve[12];
    #pragma unroll
    for (int j = 0; j < 12; ++j) { vd[j] = 0ULL; ve[j] = ~0ULL; }
    for (int g = lo; g <= hi; ++g) {
        u64 row[12];
        #pragma unroll
        for (int j = 0; j < 12; ++j) {
            const int wj = w0 + j;
            row[j] = B[g * 16 + min(max(wj, 0), 15)];   // clamped addr, L1-hot
        }
        #pragma unroll
        for (int j = 0; j < 12; ++j) {
            const int wj = w0 + j;
            const bool ok = (wj >= 0) && (wj <= 15);
            vd[j] |= ok ? row[j] : 0ULL;
            ve[j] &= ok ? row[j] : ~0ULL;
        }
    }
    // horizontal +-2 (R6-verified formula; vd[4+k] is my word W=4itg+k)
    u64 em[4], ct[4];
    #pragma unroll
    for (int k = 0; k < 4; ++k) {
        u64 hd = vd[4 + k], he = ve[4 + k];
        #pragma unroll
        for (int di = 0; di < 4; ++di) {
            const int d  = (di < 2) ? di - 2 : di - 1;   // -2,-1,1,2
            const int kp = k + d;
            u64 td, te2;
            if (kp >= 0 && kp <= 3) { td = vd[4 + k + d];            te2 = ve[4 + k + d]; }
            else if (kp > 3) { td  = (vd[k + d] >> 1) | (vd[4 + k + d] << 63);
                               te2 = (ve[k + d] >> 1) | (ve[4 + k + d] << 63); }
            else             { td  = (vd[8 + k + d] << 1) | (vd[4 + k + d] >> 63);
                               te2 = (ve[8 + k + d] << 1) | (ve[4 + k + d] >> 63); }
            hd |= td; he &= te2;
        }
        em[k] = hd & ~he;
        ct[k] = B[r * 16 + 4 * itg + k];
    }
    // bit-transpose interleaved->linear: Lj bit b = src[b&3] bit(16j + (b>>2))
    const int Lbase = img * 16384 + r * 16 + 4 * itg;
    #pragma unroll
    for (int j = 0; j < 4; ++j) {
        u64 tL = spread4(ct[0] >> (16 * j)) | (spread4(ct[1] >> (16 * j)) << 1)
               | (spread4(ct[2] >> (16 * j)) << 2) | (spread4(ct[3] >> (16 * j)) << 3);
        u64 eL = spread4(em[0] >> (16 * j)) | (spread4(em[1] >> (16 * j)) << 1)
               | (spread4(em[2] >> (16 * j)) << 2) | (spread4(em[3] >> (16 * j)) << 3);
        ulonglong2 o; o.x = tL; o.y = eL;
        TE[Lbase + j] = o;
    }
}

// ---- k3: loss stream: 2 loads/iteration, 8-deep staging -------------------
__global__ __launch_bounds__(256) void bbl_loss(
        const float* __restrict__ pred, const ulonglong2* __restrict__ TE,
        double* __restrict__ dws) {
    __shared__ float rs1[4], rse[4];
    const int tid = threadIdx.x, lane = tid & 63, wid = tid >> 6;
    const int qb = blockIdx.x * 4096 + tid;
    const float4* P = (const float4*)pred;
    float s1 = 0.f, se = 0.f;

    #pragma unroll
    for (int half = 0; half < 2; ++half) {
        float4 p[8]; ulonglong2 te[8];
        #pragma unroll
        for (int j = 0; j < 8; ++j) {
            const int q = qb + (half * 8 + j) * 256;
            p[j]  = P[q];
            te[j] = TE[q >> 4];
        }
        #pragma unroll
        for (int j = 0; j < 8; ++j) {
            const int q  = qb + (half * 8 + j) * 256;
            const int sh = (q & 15) * 4;
            const unsigned tn = (unsigned)(te[j].x >> sh) & 0xFu;
            const unsigned en = (unsigned)(te[j].y >> sh) & 0xFu;
            const float4 v = p[j];
            float x, loss;
            x = v.x;
            loss = fmaxf(x, 0.f) + __logf(1.f + __expf(-fabsf(x))) - ((tn & 1u) ? x : 0.f);
            s1 += loss; se += (en & 1u) ? loss : 0.f;
            x = v.y;
            loss = fmaxf(x, 0.f) + __logf(1.f + __expf(-fabsf(x))) - ((tn & 2u) ? x : 0.f);
            s1 += loss; se += (en & 2u) ? loss : 0.f;
            x = v.z;
            loss = fmaxf(x, 0.f) + __logf(1.f + __expf(-fabsf(x))) - ((tn & 4u) ? x : 0.f);
            s1 += loss; se += (en & 4u) ? loss : 0.f;
            x = v.w;
            loss = fmaxf(x, 0.f) + __logf(1.f + __expf(-fabsf(x))) - ((tn & 8u) ? x : 0.f);
            s1 += loss; se += (en & 8u) ? loss : 0.f;
        }
    }

    for (int off = 32; off > 0; off >>= 1) {
        s1 += __shfl_down(s1, off);
        se += __shfl_down(se, off);
    }
    if (lane == 0) { rs1[wid] = s1; rse[wid] = se; }
    __syncthreads();
    if (tid == 0) {
        atomicAdd(&dws[0], (double)(rs1[0] + rs1[1] + rs1[2] + rs1[3]));
        atomicAdd(&dws[1], (double)(rse[0] + rse[1] + rse[2] + rse[3]));
    }
}

__global__ void bbl_fin(const double* __restrict__ dws,
                        const unsigned* __restrict__ uws,
                        float* __restrict__ out) {
    if (threadIdx.x == 0) {
        float fmin = decf(uws[0]);
        float fmax = decf(uws[1]);
        bool cond = (fmax == 1.0f) && (fmin == 0.0f);
        double s = cond ? (dws[0] - 0.9 * dws[1]) : dws[0];
        out[0] = (float)(s / NTOT);
    }
}

// ---- fallback (R5-verified fused kernel) if ws too small ------------------
__device__ __forceinline__ u64 shfl64(u64 v, int src) {
    unsigned lo = (unsigned)__shfl((int)(unsigned)(v & 0xffffffffULL), src, 64);
    unsigned hi = (unsigned)__shfl((int)(unsigned)(v >> 32), src, 64);
    return ((u64)hi << 32) | lo;
}
__device__ __forceinline__ u64 bcast64(u64 v, int srcImm) {
    unsigned lo = (unsigned)__builtin_amdgcn_readlane((int)(unsigned)(v & 0xffffffffULL), srcImm);
    unsigned hi = (unsigned)__builtin_amdgcn_readlane((int)(unsigned)(v >> 32), srcImm);
    return ((u64)hi << 32) | lo;
}

__global__ __launch_bounds__(256) void bbl_fallback(
        const float* __restrict__ pred,
        const float* __restrict__ target,
        double* __restrict__ dws, unsigned* __restrict__ uws) {
    __shared__ float    redS1[4], redSe[4];
    __shared__ unsigned redMn[4], redMx[4];
    const int tid = threadIdx.x, lane = tid & 63, wid = tid >> 6;
    const int gw = blockIdx.x * 4 + wid;
    const int img = gw >> 7;
    const int r0 = (gw & 127) * 8;
    const size_t base = (size_t)img * IMG * IMG;
    const float* tbase = target + base;
    const float* pbase = pred + base;
    const int w = lane & 15, k = w & 3;
    float vmin = 3.4e38f, vmax = -3.4e38f, s1 = 0.f, se = 0.f;

    auto loadrow = [&](int gr, bool mm) -> u64 {
        const float4* rp = (const float4*)(tbase + (size_t)gr * IMG);
        u64 myw = 0ULL;
        #pragma unroll
        for (int it = 0; it < 4; ++it) {
            float4 v = rp[it * 64 + lane];
            if (mm) {
                vmin = fminf(vmin, fminf(fminf(v.x, v.y), fminf(v.z, v.w)));
                vmax = fmaxf(vmax, fmaxf(fmaxf(v.x, v.y), fmaxf(v.z, v.w)));
            }
            u64 b0 = __ballot(v.x > 0.5f), b1 = __ballot(v.y > 0.5f);
            u64 b2 = __ballot(v.z > 0.5f), b3 = __ballot(v.w > 0.5f);
            u64 bw = (k == 0) ? b0 : (k == 1) ? b1 : (k == 2) ? b2 : b3;
            if ((w >> 2) == it) myw = bw;
        }
        return myw;
    };

    u64 q0 = loadrow(max(r0 - 2, 0), false);
    u64 q1 = loadrow(max(r0 - 1, 0), false);
    u64 q2 = loadrow(r0, true);
    u64 q3 = loadrow(r0 + 1, true);

    for (int r = r0; r < r0 + 8; ++r) {
        const int nr = min(r + 2, IMG - 1);
        u64 q4 = loadrow(nr, r + 2 <= r0 + 7);
        const float4* pp = (const float4*)(pbase + (size_t)r * IMG);
        float4 p0 = pp[0 * 64 + lane], p1 = pp[1 * 64 + lane];
        float4 p2 = pp[2 * 64 + lane], p3 = pp[3 * 64 + lane];
        u64 vd = q0 | q1 | q2 | q3 | q4;
        u64 ve = q0 & q1 & q2 & q3 & q4;
        u64 ct = q2, hd = vd, he = ve;
        #pragma unroll
        for (int di = 0; di < 4; ++di) {
            const int d = (di < 2) ? di - 2 : di - 1;
            int wp = w + d;
            bool inp = (wp >= 0) && (wp < 16);
            u64 ad = shfl64(vd, wp & 15), ae = shfl64(ve, wp & 15);
            ad = inp ? ad : 0ULL; ae = inp ? ae : ~0ULL;
            int ws2 = wp + ((d > 0) ? -4 : 4);
            u64 bd = shfl64(vd, ws2 & 15), be = shfl64(ve, ws2 & 15);
            int kp = k + d;
            u64 rd, re;
            if (d > 0) {
                rd = (kp <= 3) ? ad : ((bd >> 1) | (ad << 63));
                re = (kp <= 3) ? ae : ((be >> 1) | (ae << 63));
            } else {
                rd = (kp >= 0) ? ad : ((bd << 1) | (ad >> 63));
                re = (kp >= 0) ? ae : ((be << 1) | (ae >> 63));
            }
            hd |= rd; he &= re;
        }
        u64 em = hd & ~he;
        #pragma unroll
        for (int it = 0; it < 4; ++it) {
            float4 p = (it == 0) ? p0 : (it == 1) ? p1 : (it == 2) ? p2 : p3;
            #pragma unroll
            for (int m = 0; m < 4; ++m) {
                u64 ew = bcast64(em, it * 4 + m);
                u64 tw = bcast64(ct, it * 4 + m);
                float x = (m == 0) ? p.x : (m == 1) ? p.y : (m == 2) ? p.z : p.w;
                float xt = ((tw >> lane) & 1ULL) ? x : 0.f;
                float loss = fmaxf(x, 0.f) + __logf(1.f + __expf(-fabsf(x))) - xt;
                s1 += loss; se += ((ew >> lane) & 1ULL) ? loss : 0.f;
            }
        }
        q0 = q1; q1 = q2; q2 = q3; q3 = q4;
    }
    for (int off = 32; off > 0; off >>= 1) {
        s1 += __shfl_down(s1, off); se += __shfl_down(se, off);
        vmin = fminf(vmin, __shfl_down(vmin, off));
        vmax = fmaxf(vmax, __shfl_down(vmax, off));
    }
    if (lane == 0) {
        redS1[wid] = s1; redSe[wid] = se;
        redMn[wid] = encf(vmin); redMx[wid] = encf(vmax);
    }
    __syncthreads();
    if (tid == 0) {
        float S1 = 0.f, Se = 0.f; unsigned mn = 0xFFFFFFFFu, mx = 0u;
        #pragma unroll
        for (int i = 0; i < 4; ++i) {
            S1 += redS1[i]; Se += redSe[i];
            mn = min(mn, redMn[i]); mx = max(mx, redMx[i]);
        }
        atomicAdd(&dws[0], (double)S1); atomicAdd(&dws[1], (double)Se);
        atomicMin(&uws[0], mn); atomicMax(&uws[1], mx);
    }
}

extern "C" void kernel_launch(void* const* d_in, const int* in_sizes, int n_in,
                              void* d_out, int out_size, void* d_ws, size_t ws_size,
                              hipStream_t stream) {
    const float* pred   = (const float*)d_in[0];
    const float* target = (const float*)d_in[1];
    double*   dws = (double*)d_ws;
    unsigned* uws = (unsigned*)((char*)d_ws + 16);
    float*    out = (float*)d_out;

    // ws: [0,16) dws, [16,24) uws, [4096, +4MB) Bm, then TE (8MB)
    const size_t MASKB = 4194304;
    const size_t need  = 4096 + MASKB + 2 * MASKB;
    u64*        Bm = (u64*)((char*)d_ws + 4096);
    ulonglong2* TE = (ulonglong2*)((char*)d_ws + 4096 + MASKB);

    hipLaunchKernelGGL(bbl_init, dim3(1), dim3(64), 0, stream, dws, uws);
    if (ws_size >= need) {
        hipLaunchKernelGGL(bbl_mask, dim3(GRID), dim3(256), 0, stream, target, Bm, uws);
        hipLaunchKernelGGL(bbl_edge, dim3(512), dim3(256), 0, stream, Bm, TE);
        hipLaunchKernelGGL(bbl_loss, dim3(GRID), dim3(256), 0, stream, pred, TE, dws);
    } else {
        hipLaunchKernelGGL(bbl_fallback, dim3(1024), dim3(256), 0, stream,
                           pred, target, dws, uws);
    }
    hipLaunchKernelGGL(bbl_fin, dim3(1), dim3(64), 0, stream, dws, uws, out);
}